// Round 11
// baseline (252.636 us; speedup 1.0000x reference)
//
#include <hip/hip_runtime.h>

typedef __attribute__((ext_vector_type(4))) float f32x4;
typedef __attribute__((ext_vector_type(8))) short bf16x8;
typedef unsigned short USHORT;

static __device__ __forceinline__ float bf2f(USHORT u) {
    return __uint_as_float(((unsigned)u) << 16);
}
static __device__ __forceinline__ USHORT f2bf(float f) {
    unsigned u = __float_as_uint(f);
    unsigned r = u + 0x7FFF + ((u >> 16) & 1);   // RTNE
    return (USHORT)(r >> 16);
}

#define GLDS16(gp, lp) __builtin_amdgcn_global_load_lds(                      \
    (const __attribute__((address_space(1))) unsigned int*)(gp),              \
    (__attribute__((address_space(3))) unsigned int*)(lp), 16, 0, 0)

#define FULL_BARRIER() asm volatile("s_waitcnt vmcnt(0) lgkmcnt(0)\ns_barrier" ::: "memory")

#define D64 0.52559648f              // 0.99^64
#define L2D (-0.014499569695115089f) // log2(0.99)

// ---------------------------------------------------------------------------
// Prep: z<5 -> transpose+cast weight z (fp32 [K,N] -> bf16 [N,K]);
//       z==5 -> cast x fp32->bf16 (flat).
// ---------------------------------------------------------------------------
struct PrepArgs { const float* src[5]; USHORT* dst[5]; const float* x; USHORT* xb; };

__global__ __launch_bounds__(256) void k_prep(PrepArgs pa) {
    const int z = blockIdx.z;
    const int tid = threadIdx.x;
    __shared__ USHORT t[64][65];
    if (z < 5) {
        const float* __restrict__ W  = pa.src[z];
        USHORT* __restrict__      WT = pa.dst[z];
        const int k0 = blockIdx.y * 64, n0 = blockIdx.x * 64;
#pragma unroll
        for (int s = 0; s < 4; s++) {
            int slot = tid + s * 256;
            int row = slot >> 4, c4 = (slot & 15) * 4;
            float4 vv = *(const float4*)&W[(size_t)(k0 + row) * 1024 + n0 + c4];
            t[row][c4 + 0] = f2bf(vv.x);
            t[row][c4 + 1] = f2bf(vv.y);
            t[row][c4 + 2] = f2bf(vv.z);
            t[row][c4 + 3] = f2bf(vv.w);
        }
        __syncthreads();
#pragma unroll
        for (int s = 0; s < 2; s++) {
            int slot = tid + s * 256;
            int n = slot >> 3, c8 = (slot & 7) * 8;
            USHORT tmp[8];
#pragma unroll
            for (int u = 0; u < 8; u++) tmp[u] = t[c8 + u][n];
            *(int4*)&WT[(size_t)(n0 + n) * 1024 + k0 + c8] = *(int4*)tmp;
        }
    } else {
        const int bi = blockIdx.y * 16 + blockIdx.x;          // 0..255
        const float* xs = pa.x + (size_t)bi * 16384;
        USHORT* xd = pa.xb + (size_t)bi * 16384;
#pragma unroll
        for (int u = 0; u < 16; u++) {
            int idx = u * 1024 + tid * 4;
            float4 v = *(const float4*)&xs[idx];
            *(ushort4*)&xd[idx] = make_ushort4(f2bf(v.x), f2bf(v.y), f2bf(v.z), f2bf(v.w));
        }
    }
}

// ---------------------------------------------------------------------------
// GEMM. A-staging: ln==0 -> bf16 glds; ln==1 -> fused LayerNorm+gate staging
// (A = bf16((R - mu)*inv*gamma + beta) * G, stats per row).
// Epilogue modes: 0 bf16; 1 sigmoid bf16; 2 V->VT[b,h,d,s]*0.99^{-(s&63)};
// 3 fp32; 4 bf16 * scale * 0.99^{row&63} (Q'').
// ---------------------------------------------------------------------------
struct GArgs {
    const USHORT* A;          // bf16 A (glds) or R (ln path)
    const USHORT* G;          // gate (ln path)
    const float*  gamma;
    const float*  beta;
    const float*  stats;      // [4096][2] fp32 (sum, sumsq)
    int           ln;
    const USHORT* W[4];
    const float*  bias[4];
    void*         dst[4];
    USHORT*       dstv;
    float         scale[4];
    int           mode[4];
};

__global__ __launch_bounds__(256, 2) void k_gemm(GArgs ga) {
    const int z = blockIdx.z;
    const USHORT* __restrict__ BT = ga.W[z];
    __shared__ USHORT As[2][128 * 32];
    __shared__ USHORT Bs[2][128 * 32];
    const int tid = threadIdx.x;
    const int m0 = blockIdx.y * 128, n0 = blockIdx.x * 128;
    const int w = tid >> 6, l = tid & 63, lr = l & 15, q = l >> 4;
    const int wr = w >> 1, wc = w & 1;
    const int srow = tid >> 2, sco = (tid & 3) * 8;
    f32x4 acc[4][4] = {};
    float mu0 = 0.f, iv0 = 0.f, mu1 = 0.f, iv1 = 0.f;
    if (ga.ln) {
        float2 s0 = *(const float2*)&ga.stats[(m0 + srow) * 2];
        mu0 = s0.x * (1.0f / 1024.0f);
        iv0 = rsqrtf(fmaxf(s0.y * (1.0f / 1024.0f) - mu0 * mu0, 0.0f) + 1e-5f);
        float2 s1 = *(const float2*)&ga.stats[(m0 + srow + 64) * 2];
        mu1 = s1.x * (1.0f / 1024.0f);
        iv1 = rsqrtf(fmaxf(s1.y * (1.0f / 1024.0f) - mu1 * mu1, 0.0f) + 1e-5f);
    }
#define STAGE_A(kt_, buf_)                                                       \
    do {                                                                         \
        const int kk0 = (kt_) * 32;                                              \
        if (ga.ln) {                                                             \
            float4 g0 = *(const float4*)&ga.gamma[kk0 + sco];                    \
            float4 g1 = *(const float4*)&ga.gamma[kk0 + sco + 4];                \
            float4 b0 = *(const float4*)&ga.beta[kk0 + sco];                     \
            float4 b1 = *(const float4*)&ga.beta[kk0 + sco + 4];                 \
            float gmv[8] = {g0.x,g0.y,g0.z,g0.w,g1.x,g1.y,g1.z,g1.w};            \
            float btv[8] = {b0.x,b0.y,b0.z,b0.w,b1.x,b1.y,b1.z,b1.w};            \
            _Pragma("unroll")                                                    \
            for (int hrow = 0; hrow < 2; hrow++) {                               \
                float mu = hrow ? mu1 : mu0, iv = hrow ? iv1 : iv0;              \
                size_t off = (size_t)(m0 + srow + hrow * 64) * 1024 + kk0 + sco; \
                USHORT r8[8], g8[8], a8[8];                                      \
                *(int4*)r8 = *(const int4*)&ga.A[off];                           \
                *(int4*)g8 = *(const int4*)&ga.G[off];                           \
                _Pragma("unroll")                                                \
                for (int u = 0; u < 8; u++)                                      \
                    a8[u] = f2bf(((bf2f(r8[u]) - mu) * iv * gmv[u] + btv[u])     \
                                 * bf2f(g8[u]));                                 \
                *(int4*)&As[buf_][(srow + hrow * 64) * 32 + sco] = *(int4*)a8;   \
            }                                                                    \
        } else {                                                                 \
            GLDS16(&ga.A[(size_t)(m0 + srow) * 1024 + kk0 + sco],                \
                   &As[buf_][srow * 32 + sco]);                                  \
            GLDS16(&ga.A[(size_t)(m0 + srow + 64) * 1024 + kk0 + sco],           \
                   &As[buf_][(srow + 64) * 32 + sco]);                           \
        }                                                                        \
        GLDS16(&BT[(size_t)(n0 + srow) * 1024 + kk0 + sco],                      \
               &Bs[buf_][srow * 32 + sco]);                                      \
        GLDS16(&BT[(size_t)(n0 + srow + 64) * 1024 + kk0 + sco],                 \
               &Bs[buf_][(srow + 64) * 32 + sco]);                               \
    } while (0)
    STAGE_A(0, 0);
    for (int kt = 0; kt < 32; kt++) {
        const int cur = kt & 1;
        FULL_BARRIER();
        if (kt + 1 < 32) STAGE_A(kt + 1, 1 - cur);
        bf16x8 af[4], bfr[4];
#pragma unroll
        for (int mi = 0; mi < 4; mi++)
            af[mi] = *(const bf16x8*)&As[cur][(wr * 64 + mi * 16 + lr) * 32 + q * 8];
#pragma unroll
        for (int ni = 0; ni < 4; ni++)
            bfr[ni] = *(const bf16x8*)&Bs[cur][(wc * 64 + ni * 16 + lr) * 32 + q * 8];
#pragma unroll
        for (int mi = 0; mi < 4; mi++)
#pragma unroll
            for (int ni = 0; ni < 4; ni++)
                acc[mi][ni] = __builtin_amdgcn_mfma_f32_16x16x32_bf16(
                    af[mi], bfr[ni], acc[mi][ni], 0, 0, 0);
    }
#undef STAGE_A
    const float scale = ga.scale[z];
    const int mode = ga.mode[z];
    const float* __restrict__ bias = ga.bias[z];
#pragma unroll
    for (int ni = 0; ni < 4; ni++) {
        int col = n0 + wc * 64 + ni * 16 + lr;
        float bv = bias[col];
#pragma unroll
        for (int mi = 0; mi < 4; mi++) {
            int r0 = m0 + wr * 64 + mi * 16 + q * 4;
            float vr[4];
#pragma unroll
            for (int r = 0; r < 4; r++) {
                float v = acc[mi][ni][r] + bv;
                if (mode == 1) v = 1.0f / (1.0f + __expf(-v));
                vr[r] = v * scale;
            }
            if (mode == 4) {
                float d0 = exp2f(L2D * (float)(r0 & 63));
                vr[0] *= d0;
                vr[1] *= d0 * 0.99f;
                vr[2] *= d0 * 0.9801f;
                vr[3] *= d0 * 0.970299f;
            }
            if (mode == 3) {
                float* df = (float*)ga.dst[z];
#pragma unroll
                for (int r = 0; r < 4; r++)
                    df[(size_t)(r0 + r) * 1024 + col] = vr[r];
            } else if (mode == 2) {
                int b = r0 >> 11, s = r0 & 2047;
                int h = col >> 6, d = col & 63;
                const float NP1 = 1.0101010101010102f;
                float c0 = exp2f(-L2D * (float)(s & 63));
                float c1 = c0 * NP1, c2 = c1 * NP1, c3 = c2 * NP1;
                *(ushort4*)&ga.dstv[(size_t)(((b * 16 + h) * 64) + d) * 2048 + s] =
                    make_ushort4(f2bf(vr[0] * c0), f2bf(vr[1] * c1),
                                 f2bf(vr[2] * c2), f2bf(vr[3] * c3));
            } else {
                USHORT* db = (USHORT*)ga.dst[z];
#pragma unroll
                for (int r = 0; r < 4; r++)
                    db[(size_t)(r0 + r) * 1024 + col] = f2bf(vr[r]);
            }
        }
    }
}

// ---------------------------------------------------------------------------
// U_c = 0.99^64 * V'_c^T @ K_c  fp32 at slot (bh,c) in U (=d_out).
// ---------------------------------------------------------------------------
__global__ __launch_bounds__(256) void k_attn_u(const USHORT* __restrict__ K,
                                                const USHORT* __restrict__ VT,
                                                float* __restrict__ U) {
    const int bh = blockIdx.x, c = blockIdx.y;
    const int b = bh >> 4, h = bh & 15;
    const int tid = threadIdx.x, w = tid >> 6, l = tid & 63, lr = l & 15, q = l >> 4;
    __shared__ USHORT KT[64 * 72];
    __shared__ USHORT Vs[64 * 72];
#pragma unroll
    for (int s = 0; s < 2; s++) {
        int slot = tid + s * 256;
        int row = slot >> 3, co = (slot & 7) * 8;
        USHORT kv[8];
        *(int4*)kv = *(const int4*)&K[(size_t)(b * 2048 + c * 64 + row) * 1024 + h * 64 + co];
#pragma unroll
        for (int u = 0; u < 8; u++) KT[(co + u) * 72 + row] = kv[u];
        *(int4*)&Vs[row * 72 + co] =
            *(const int4*)&VT[(size_t)(bh * 64 + row) * 2048 + c * 64 + co];
    }
    __syncthreads();
    f32x4 acc[4] = {};
    bf16x8 av[2];
#pragma unroll
    for (int kk = 0; kk < 2; kk++)
        av[kk] = *(const bf16x8*)&Vs[(w * 16 + lr) * 72 + kk * 32 + q * 8];
#pragma unroll
    for (int dkt = 0; dkt < 4; dkt++)
#pragma unroll
        for (int kk = 0; kk < 2; kk++) {
            bf16x8 bk = *(const bf16x8*)&KT[(dkt * 16 + lr) * 72 + kk * 32 + q * 8];
            acc[dkt] = __builtin_amdgcn_mfma_f32_16x16x32_bf16(av[kk], bk, acc[dkt], 0, 0, 0);
        }
    float* slot = U + (size_t)(bh * 32 + c) * 4096;
#pragma unroll
    for (int dkt = 0; dkt < 4; dkt++)
#pragma unroll
        for (int r = 0; r < 4; r++)
            slot[(w * 16 + q * 4 + r) * 64 + dkt * 16 + lr] = acc[dkt][r] * D64;
}

// ---------------------------------------------------------------------------
// Apply: block (bh, c): scan U->S_{c-1} (packed hi/lo in LDS), diag masked
// tile, cross via S, LN stats (fp32, atomics), R bf16 written IN-PLACE over K
// (each block writes exactly the region only it staged). Wave w: 16 i-rows.
// ---------------------------------------------------------------------------
__global__ __launch_bounds__(256, 2) void k_apply(const USHORT* __restrict__ Q,
                                                  const USHORT* __restrict__ K,
                                                  const USHORT* __restrict__ VT,
                                                  const float* __restrict__ U,
                                                  USHORT* __restrict__ R,
                                                  float* __restrict__ stats) {
    const int bh = blockIdx.x, c = blockIdx.y;
    const int b = bh >> 4, h = bh & 15;
    const int i0 = c * 64;
    const int tid = threadIdx.x, w = tid >> 6, l = tid & 63, lr = l & 15, q = l >> 4;
    __shared__ USHORT Qs[64 * 72];
    __shared__ USHORT Ks[64 * 72];
    __shared__ USHORT Vs[64 * 72];
    __shared__ USHORT Ps[4][16 * 72];
    __shared__ unsigned Spk[4096];
    // stage Q'', K (rows i0..i0+63, head h), V' (d x s tile)
#pragma unroll
    for (int s = 0; s < 2; s++) {
        int slot = tid + s * 256;
        int row = slot >> 3, c8 = (slot & 7) * 8;
        *(int4*)&Qs[row * 72 + c8] =
            *(const int4*)&Q[(size_t)(b * 2048 + i0 + row) * 1024 + h * 64 + c8];
        *(int4*)&Ks[row * 72 + c8] =
            *(const int4*)&K[(size_t)(b * 2048 + i0 + row) * 1024 + h * 64 + c8];
        *(int4*)&Vs[row * 72 + c8] =
            *(const int4*)&VT[(size_t)(bh * 64 + row) * 2048 + i0 + c8];
    }
    // scan: S_{c-1} = sum_{c'<c} D64^{c-1-c'} U_{c'}  (U already has one D64)
    if (c > 0) {
        float sa[16] = {};
        const float* Ub = U + (size_t)bh * 32 * 4096 + tid * 16;
        for (int cp = 0; cp < c; cp++) {
            const float* p = Ub + (size_t)cp * 4096;
#pragma unroll
            for (int u4 = 0; u4 < 4; u4++) {
                float4 uv = *(const float4*)(p + u4 * 4);
                sa[u4 * 4 + 0] = sa[u4 * 4 + 0] * D64 + uv.x;
                sa[u4 * 4 + 1] = sa[u4 * 4 + 1] * D64 + uv.y;
                sa[u4 * 4 + 2] = sa[u4 * 4 + 2] * D64 + uv.z;
                sa[u4 * 4 + 3] = sa[u4 * 4 + 3] * D64 + uv.w;
            }
        }
#pragma unroll
        for (int u = 0; u < 16; u++) {
            USHORT hi = f2bf(sa[u]);
            float  lo = sa[u] - bf2f(hi);
            Spk[tid * 16 + u] = (unsigned)hi | ((unsigned)f2bf(lo) << 16);
        }
    }
    __syncthreads();
    bf16x8 bqf[2];
#pragma unroll
    for (int kk = 0; kk < 2; kk++)
        bqf[kk] = *(const bf16x8*)&Qs[(w * 16 + lr) * 72 + kk * 32 + q * 8];
    f32x4 accr[4] = {};
    // cross: out^T[d][i] += (S_hi + S_lo) @ Q''
    if (c > 0) {
#pragma unroll
        for (int dt = 0; dt < 4; dt++)
#pragma unroll
            for (int kk = 0; kk < 2; kk++) {
                const unsigned* sp = &Spk[(dt * 16 + lr) * 64 + kk * 32 + q * 8];
                uint4 pa = *(const uint4*)sp;
                uint4 pb = *(const uint4*)(sp + 4);
                unsigned pk[8] = { pa.x, pa.y, pa.z, pa.w, pb.x, pb.y, pb.z, pb.w };
                bf16x8 hi, lo;
#pragma unroll
                for (int u = 0; u < 8; u++) {
                    hi[u] = (short)(pk[u] & 0xffffu);
                    lo[u] = (short)(pk[u] >> 16);
                }
                accr[dt] = __builtin_amdgcn_mfma_f32_16x16x32_bf16(hi, bqf[kk], accr[dt], 0, 0, 0);
                accr[dt] = __builtin_amdgcn_mfma_f32_16x16x32_bf16(lo, bqf[kk], accr[dt], 0, 0, 0);
            }
    }
    // diag: P^T = K @ Q''^T, mask, pack, PV'
    {
        f32x4 accp[4] = {};
#pragma unroll
        for (int kk = 0; kk < 2; kk++)
#pragma unroll
            for (int jt = 0; jt < 4; jt++) {
                bf16x8 akf = *(const bf16x8*)&Ks[(jt * 16 + lr) * 72 + kk * 32 + q * 8];
                accp[jt] = __builtin_amdgcn_mfma_f32_16x16x32_bf16(akf, bqf[kk], accp[jt], 0, 0, 0);
            }
        const int ii = w * 16 + lr;          // local i (0..63)
#pragma unroll
        for (int jt = 0; jt < 4; jt++) {
            const int jj = jt * 16 + q * 4;  // local j
            float v0 = (jj + 0 <= ii) ? accp[jt][0] : 0.0f;
            float v1 = (jj + 1 <= ii) ? accp[jt][1] : 0.0f;
            float v2 = (jj + 2 <= ii) ? accp[jt][2] : 0.0f;
            float v3 = (jj + 3 <= ii) ? accp[jt][3] : 0.0f;
            unsigned w0 = __builtin_amdgcn_perm(
                __float_as_uint(v1), __float_as_uint(v0), 0x07060302u);
            unsigned w1 = __builtin_amdgcn_perm(
                __float_as_uint(v3), __float_as_uint(v2), 0x07060302u);
            *(uint2*)&Ps[w][lr * 72 + jt * 16 + q * 4] = make_uint2(w0, w1);
        }
        asm volatile("s_waitcnt lgkmcnt(0)" ::: "memory");
#pragma unroll
        for (int kk = 0; kk < 2; kk++) {
            bf16x8 bpf = *(const bf16x8*)&Ps[w][lr * 72 + kk * 32 + q * 8];
#pragma unroll
            for (int dt = 0; dt < 4; dt++) {
                bf16x8 avf = *(const bf16x8*)&Vs[(dt * 16 + lr) * 72 + kk * 32 + q * 8];
                accr[dt] = __builtin_amdgcn_mfma_f32_16x16x32_bf16(avf, bpf, accr[dt], 0, 0, 0);
            }
        }
    }
    // LN stats: per row i, sum & sumsq over this head's 64 d values
    {
        float s1 = 0.f, s2 = 0.f;
#pragma unroll
        for (int dt = 0; dt < 4; dt++)
#pragma unroll
            for (int r = 0; r < 4; r++) {
                float v = accr[dt][r];
                s1 += v; s2 += v * v;
            }
        s1 += __shfl_down(s1, 32); s2 += __shfl_down(s2, 32);
        s1 += __shfl_down(s1, 16); s2 += __shfl_down(s2, 16);
        if (q == 0) {
            int row = b * 2048 + i0 + w * 16 + lr;
            atomicAdd(&stats[row * 2 + 0], s1);
            atomicAdd(&stats[row * 2 + 1], s2);
        }
    }
    // write R bf16 in-place over K's staged region
    {
        const int i = i0 + w * 16 + lr;
#pragma unroll
        for (int dt = 0; dt < 4; dt++) {
            f32x4 a = accr[dt];
            *(ushort4*)&R[(size_t)(b * 2048 + i) * 1024 + h * 64 + dt * 16 + q * 4] =
                make_ushort4(f2bf(a[0]), f2bf(a[1]), f2bf(a[2]), f2bf(a[3]));
        }
    }
}

// ---------------------------------------------------------------------------
extern "C" void kernel_launch(void* const* d_in, const int* in_sizes, int n_in,
                              void* d_out, int out_size, void* d_ws, size_t ws_size,
                              hipStream_t stream) {
    const float* x     = (const float*)d_in[0];
    const float* Wq    = (const float*)d_in[1];
    const float* bq    = (const float*)d_in[2];
    const float* Wk    = (const float*)d_in[3];
    const float* bk    = (const float*)d_in[4];
    const float* Wv    = (const float*)d_in[5];
    const float* bv    = (const float*)d_in[6];
    const float* Wg    = (const float*)d_in[7];
    const float* bg    = (const float*)d_in[8];
    const float* Wo    = (const float*)d_in[9];
    const float* bo    = (const float*)d_in[10];
    const float* gamma = (const float*)d_in[11];
    const float* beta  = (const float*)d_in[12];

    // ws (42 MB + 32 KB): WT x5 | Qb (Q'') | Kb -> R bf16 (in-place) | VTb | Gb | stats
    char* ws = (char*)d_ws;
    const size_t MB = 1 << 20;
    USHORT* WqT = (USHORT*)(ws + 0 * MB);
    USHORT* WkT = (USHORT*)(ws + 2 * MB);
    USHORT* WvT = (USHORT*)(ws + 4 * MB);
    USHORT* WgT = (USHORT*)(ws + 6 * MB);
    USHORT* WoT = (USHORT*)(ws + 8 * MB);
    USHORT* Qb  = (USHORT*)(ws + 10 * MB);
    USHORT* Kb  = (USHORT*)(ws + 18 * MB);   // becomes R bf16 after k_apply
    USHORT* VTb = (USHORT*)(ws + 26 * MB);
    USHORT* Gb  = (USHORT*)(ws + 34 * MB);
    float*  Sts = (float*) (ws + 42 * MB);   // 4096 x 2 fp32
    USHORT* Xb  = (USHORT*)d_out;            // bf16 x; dead after proj
    float*  Ust = (float*)d_out;             // U slots (16 MB); dead after apply

    {   // 1. prep: transpose 5 weights + cast x
        PrepArgs pa;
        pa.src[0] = Wq; pa.src[1] = Wk; pa.src[2] = Wv; pa.src[3] = Wg; pa.src[4] = Wo;
        pa.dst[0] = WqT; pa.dst[1] = WkT; pa.dst[2] = WvT; pa.dst[3] = WgT; pa.dst[4] = WoT;
        pa.x = x; pa.xb = Xb;
        k_prep<<<dim3(16, 16, 6), 256, 0, stream>>>(pa);
    }
    hipMemsetAsync((void*)Sts, 0, 4096 * 2 * sizeof(float), stream);
    {   // 2. fused projections: Q''(mode4, 1/8 + row decay), K, VT(+col decay), G(sigmoid)
        GArgs ga;
        ga.A = Xb; ga.G = nullptr; ga.gamma = gamma; ga.beta = beta;
        ga.stats = Sts; ga.ln = 0;
        ga.W[0] = WqT; ga.W[1] = WkT; ga.W[2] = WvT; ga.W[3] = WgT;
        ga.bias[0] = bq; ga.bias[1] = bk; ga.bias[2] = bv; ga.bias[3] = bg;
        ga.dst[0] = Qb; ga.dst[1] = Kb; ga.dst[2] = nullptr; ga.dst[3] = Gb;
        ga.dstv = VTb;
        ga.scale[0] = 0.125f; ga.scale[1] = 1.0f; ga.scale[2] = 1.0f; ga.scale[3] = 1.0f;
        ga.mode[0] = 4; ga.mode[1] = 0; ga.mode[2] = 2; ga.mode[3] = 1;
        k_gemm<<<dim3(8, 32, 4), 256, 0, stream>>>(ga);
    }
    // 3. chunk outer products U (into d_out; Xb dead)
    k_attn_u<<<dim3(32, 32), 256, 0, stream>>>(Kb, VTb, Ust);
    // 4. apply: scan + diag + cross + LN stats; R bf16 in-place over Kb
    k_apply<<<dim3(32, 32), 256, 0, stream>>>(Qb, Kb, VTb, Ust, Kb, Sts);
    {   // 5. output projection with fused LN+gate A-staging -> d_out fp32
        GArgs go;
        go.A = Kb;                 // R bf16
        go.G = Gb; go.gamma = gamma; go.beta = beta; go.stats = Sts; go.ln = 1;
        for (int i = 0; i < 4; i++) {
            go.W[i] = WoT; go.bias[i] = bo; go.dst[i] = d_out;
            go.scale[i] = 1.0f; go.mode[i] = 3;
        }
        go.dstv = nullptr;
        k_gemm<<<dim3(8, 32, 1), 256, 0, stream>>>(go);
    }
}

// Round 12
// 232.995 us; speedup vs baseline: 1.0843x; 1.0843x over previous
//
#include <hip/hip_runtime.h>

typedef __attribute__((ext_vector_type(4))) float f32x4;
typedef __attribute__((ext_vector_type(8))) short bf16x8;
typedef unsigned short USHORT;

static __device__ __forceinline__ float bf2f(USHORT u) {
    return __uint_as_float(((unsigned)u) << 16);
}
static __device__ __forceinline__ USHORT f2bf(float f) {
    unsigned u = __float_as_uint(f);
    unsigned r = u + 0x7FFF + ((u >> 16) & 1);   // RTNE
    return (USHORT)(r >> 16);
}

#define GLDS16(gp, lp) __builtin_amdgcn_global_load_lds(                      \
    (const __attribute__((address_space(1))) unsigned int*)(gp),              \
    (__attribute__((address_space(3))) unsigned int*)(lp), 16, 0, 0)

#define FULL_BARRIER() asm volatile("s_waitcnt vmcnt(0) lgkmcnt(0)\ns_barrier" ::: "memory")

#define D64 0.52559648f              // 0.99^64
#define L2D (-0.014499569695115089f) // log2(0.99)

// ---------------------------------------------------------------------------
// Prep: z<5 -> transpose+cast weight z (fp32 [K,N] -> bf16 [N,K]);
//       z==5 -> cast x fp32->bf16 (flat).
// ---------------------------------------------------------------------------
struct PrepArgs { const float* src[5]; USHORT* dst[5]; const float* x; USHORT* xb; };

__global__ __launch_bounds__(256) void k_prep(PrepArgs pa) {
    const int z = blockIdx.z;
    const int tid = threadIdx.x;
    __shared__ USHORT t[64][65];
    if (z < 5) {
        const float* __restrict__ W  = pa.src[z];
        USHORT* __restrict__      WT = pa.dst[z];
        const int k0 = blockIdx.y * 64, n0 = blockIdx.x * 64;
#pragma unroll
        for (int s = 0; s < 4; s++) {
            int slot = tid + s * 256;
            int row = slot >> 4, c4 = (slot & 15) * 4;
            float4 vv = *(const float4*)&W[(size_t)(k0 + row) * 1024 + n0 + c4];
            t[row][c4 + 0] = f2bf(vv.x);
            t[row][c4 + 1] = f2bf(vv.y);
            t[row][c4 + 2] = f2bf(vv.z);
            t[row][c4 + 3] = f2bf(vv.w);
        }
        __syncthreads();
#pragma unroll
        for (int s = 0; s < 2; s++) {
            int slot = tid + s * 256;
            int n = slot >> 3, c8 = (slot & 7) * 8;
            USHORT tmp[8];
#pragma unroll
            for (int u = 0; u < 8; u++) tmp[u] = t[c8 + u][n];
            *(int4*)&WT[(size_t)(n0 + n) * 1024 + k0 + c8] = *(int4*)tmp;
        }
    } else {
        const int bi = blockIdx.y * 16 + blockIdx.x;
        const float* xs = pa.x + (size_t)bi * 16384;
        USHORT* xd = pa.xb + (size_t)bi * 16384;
#pragma unroll
        for (int u = 0; u < 16; u++) {
            int idx = u * 1024 + tid * 4;
            float4 v = *(const float4*)&xs[idx];
            *(ushort4*)&xd[idx] = make_ushort4(f2bf(v.x), f2bf(v.y), f2bf(v.z), f2bf(v.w));
        }
    }
}

// ---------------------------------------------------------------------------
// LEAN projection GEMM (no LN path, bf16 A via glds only).
// modes: 0 bf16; 1 sigmoid bf16; 2 V->VT[b,h,d,s]*0.99^{-(s&63)};
//        4 bf16 * scale * 0.99^{row&63} (Q'').
// ---------------------------------------------------------------------------
struct GArgs {
    const USHORT* A;
    const USHORT* W[4];
    const float*  bias[4];
    USHORT*       dst[4];
    USHORT*       dstv;
    float         scale[4];
    int           mode[4];
};

__global__ __launch_bounds__(256, 2) void k_gemm(GArgs ga) {
    const int z = blockIdx.z;
    const USHORT* __restrict__ A  = ga.A;
    const USHORT* __restrict__ BT = ga.W[z];
    __shared__ USHORT As[2][128 * 32];
    __shared__ USHORT Bs[2][128 * 32];
    const int tid = threadIdx.x;
    const int m0 = blockIdx.y * 128, n0 = blockIdx.x * 128;
    const int w = tid >> 6, l = tid & 63, lr = l & 15, q = l >> 4;
    const int wr = w >> 1, wc = w & 1;
    const int srow = tid >> 2, sco = (tid & 3) * 8;
    f32x4 acc[4][4] = {};
    GLDS16(&A [(size_t)(m0 + srow)      * 1024 + sco], &As[0][srow * 32 + sco]);
    GLDS16(&A [(size_t)(m0 + srow + 64) * 1024 + sco], &As[0][(srow + 64) * 32 + sco]);
    GLDS16(&BT[(size_t)(n0 + srow)      * 1024 + sco], &Bs[0][srow * 32 + sco]);
    GLDS16(&BT[(size_t)(n0 + srow + 64) * 1024 + sco], &Bs[0][(srow + 64) * 32 + sco]);
    for (int kt = 0; kt < 32; kt++) {
        const int cur = kt & 1;
        FULL_BARRIER();
        if (kt + 1 < 32) {
            const int k1 = (kt + 1) * 32;
            const int nxt = 1 - cur;
            GLDS16(&A [(size_t)(m0 + srow)      * 1024 + k1 + sco], &As[nxt][srow * 32 + sco]);
            GLDS16(&A [(size_t)(m0 + srow + 64) * 1024 + k1 + sco], &As[nxt][(srow + 64) * 32 + sco]);
            GLDS16(&BT[(size_t)(n0 + srow)      * 1024 + k1 + sco], &Bs[nxt][srow * 32 + sco]);
            GLDS16(&BT[(size_t)(n0 + srow + 64) * 1024 + k1 + sco], &Bs[nxt][(srow + 64) * 32 + sco]);
        }
        bf16x8 af[4], bfr[4];
#pragma unroll
        for (int mi = 0; mi < 4; mi++)
            af[mi] = *(const bf16x8*)&As[cur][(wr * 64 + mi * 16 + lr) * 32 + q * 8];
#pragma unroll
        for (int ni = 0; ni < 4; ni++)
            bfr[ni] = *(const bf16x8*)&Bs[cur][(wc * 64 + ni * 16 + lr) * 32 + q * 8];
#pragma unroll
        for (int mi = 0; mi < 4; mi++)
#pragma unroll
            for (int ni = 0; ni < 4; ni++)
                acc[mi][ni] = __builtin_amdgcn_mfma_f32_16x16x32_bf16(
                    af[mi], bfr[ni], acc[mi][ni], 0, 0, 0);
    }
    const float scale = ga.scale[z];
    const int mode = ga.mode[z];
    const float* __restrict__ bias = ga.bias[z];
#pragma unroll
    for (int ni = 0; ni < 4; ni++) {
        int col = n0 + wc * 64 + ni * 16 + lr;
        float bv = bias[col];
#pragma unroll
        for (int mi = 0; mi < 4; mi++) {
            int r0 = m0 + wr * 64 + mi * 16 + q * 4;
            float vr[4];
#pragma unroll
            for (int r = 0; r < 4; r++) {
                float v = acc[mi][ni][r] + bv;
                if (mode == 1) v = 1.0f / (1.0f + __expf(-v));
                vr[r] = v * scale;
            }
            if (mode == 4) {
                float d0 = exp2f(L2D * (float)(r0 & 63));
                vr[0] *= d0;
                vr[1] *= d0 * 0.99f;
                vr[2] *= d0 * 0.9801f;
                vr[3] *= d0 * 0.970299f;
            }
            if (mode == 2) {
                int b = r0 >> 11, s = r0 & 2047;
                int h = col >> 6, d = col & 63;
                const float NP1 = 1.0101010101010102f;
                float c0 = exp2f(-L2D * (float)(s & 63));
                float c1 = c0 * NP1, c2 = c1 * NP1, c3 = c2 * NP1;
                *(ushort4*)&ga.dstv[(size_t)(((b * 16 + h) * 64) + d) * 2048 + s] =
                    make_ushort4(f2bf(vr[0] * c0), f2bf(vr[1] * c1),
                                 f2bf(vr[2] * c2), f2bf(vr[3] * c3));
            } else {
                USHORT* db = ga.dst[z];
#pragma unroll
                for (int r = 0; r < 4; r++)
                    db[(size_t)(r0 + r) * 1024 + col] = f2bf(vr[r]);
            }
        }
    }
}

// ---------------------------------------------------------------------------
// U_c = 0.99^64 * V'_c^T @ K_c  fp32 at slot (bh,c) in U (=d_out).
// ---------------------------------------------------------------------------
__global__ __launch_bounds__(256) void k_attn_u(const USHORT* __restrict__ K,
                                                const USHORT* __restrict__ VT,
                                                float* __restrict__ U) {
    const int bh = blockIdx.x, c = blockIdx.y;
    const int b = bh >> 4, h = bh & 15;
    const int tid = threadIdx.x, w = tid >> 6, l = tid & 63, lr = l & 15, q = l >> 4;
    __shared__ USHORT KT[64 * 72];
    __shared__ USHORT Vs[64 * 72];
#pragma unroll
    for (int s = 0; s < 2; s++) {
        int slot = tid + s * 256;
        int row = slot >> 3, co = (slot & 7) * 8;
        USHORT kv[8];
        *(int4*)kv = *(const int4*)&K[(size_t)(b * 2048 + c * 64 + row) * 1024 + h * 64 + co];
#pragma unroll
        for (int u = 0; u < 8; u++) KT[(co + u) * 72 + row] = kv[u];
        *(int4*)&Vs[row * 72 + co] =
            *(const int4*)&VT[(size_t)(bh * 64 + row) * 2048 + c * 64 + co];
    }
    __syncthreads();
    f32x4 acc[4] = {};
    bf16x8 av[2];
#pragma unroll
    for (int kk = 0; kk < 2; kk++)
        av[kk] = *(const bf16x8*)&Vs[(w * 16 + lr) * 72 + kk * 32 + q * 8];
#pragma unroll
    for (int dkt = 0; dkt < 4; dkt++)
#pragma unroll
        for (int kk = 0; kk < 2; kk++) {
            bf16x8 bk = *(const bf16x8*)&KT[(dkt * 16 + lr) * 72 + kk * 32 + q * 8];
            acc[dkt] = __builtin_amdgcn_mfma_f32_16x16x32_bf16(av[kk], bk, acc[dkt], 0, 0, 0);
        }
    float* slot = U + (size_t)(bh * 32 + c) * 4096;
#pragma unroll
    for (int dkt = 0; dkt < 4; dkt++)
#pragma unroll
        for (int r = 0; r < 4; r++)
            slot[(w * 16 + q * 4 + r) * 64 + dkt * 16 + lr] = acc[dkt][r] * D64;
}

// ---------------------------------------------------------------------------
// Apply: block (bh, c): scan U->S_{c-1} (hi/lo packed in LDS), diag masked
// tile, cross via S, per-head LN stats (unique writer, no atomics),
// R bf16 in-place over K's staged region.
// ---------------------------------------------------------------------------
__global__ __launch_bounds__(256, 2) void k_apply(const USHORT* __restrict__ Q,
                                                  const USHORT* __restrict__ K,
                                                  const USHORT* __restrict__ VT,
                                                  const float* __restrict__ U,
                                                  USHORT* __restrict__ R,
                                                  float* __restrict__ stats) {
    const int bh = blockIdx.x, c = blockIdx.y;
    const int b = bh >> 4, h = bh & 15;
    const int i0 = c * 64;
    const int tid = threadIdx.x, w = tid >> 6, l = tid & 63, lr = l & 15, q = l >> 4;
    __shared__ USHORT Qs[64 * 72];
    __shared__ USHORT Ks[64 * 72];
    __shared__ USHORT Vs[64 * 72];
    __shared__ USHORT Ps[4][16 * 72];
    __shared__ unsigned Spk[4096];
#pragma unroll
    for (int s = 0; s < 2; s++) {
        int slot = tid + s * 256;
        int row = slot >> 3, c8 = (slot & 7) * 8;
        *(int4*)&Qs[row * 72 + c8] =
            *(const int4*)&Q[(size_t)(b * 2048 + i0 + row) * 1024 + h * 64 + c8];
        *(int4*)&Ks[row * 72 + c8] =
            *(const int4*)&K[(size_t)(b * 2048 + i0 + row) * 1024 + h * 64 + c8];
        *(int4*)&Vs[row * 72 + c8] =
            *(const int4*)&VT[(size_t)(bh * 64 + row) * 2048 + i0 + c8];
    }
    // scan: S_{c-1} = sum_{c'<c} D64^{c-1-c'} U_{c'}
    if (c > 0) {
        float sa[16] = {};
        const float* Ub = U + (size_t)bh * 32 * 4096 + tid * 16;
        for (int cp = 0; cp < c; cp++) {
            const float* p = Ub + (size_t)cp * 4096;
#pragma unroll
            for (int u4 = 0; u4 < 4; u4++) {
                float4 uv = *(const float4*)(p + u4 * 4);
                sa[u4 * 4 + 0] = sa[u4 * 4 + 0] * D64 + uv.x;
                sa[u4 * 4 + 1] = sa[u4 * 4 + 1] * D64 + uv.y;
                sa[u4 * 4 + 2] = sa[u4 * 4 + 2] * D64 + uv.z;
                sa[u4 * 4 + 3] = sa[u4 * 4 + 3] * D64 + uv.w;
            }
        }
#pragma unroll
        for (int u = 0; u < 16; u++) {
            USHORT hi = f2bf(sa[u]);
            float  lo = sa[u] - bf2f(hi);
            Spk[tid * 16 + u] = (unsigned)hi | ((unsigned)f2bf(lo) << 16);
        }
    }
    __syncthreads();
    bf16x8 bqf[2];
#pragma unroll
    for (int kk = 0; kk < 2; kk++)
        bqf[kk] = *(const bf16x8*)&Qs[(w * 16 + lr) * 72 + kk * 32 + q * 8];
    f32x4 accr[4] = {};
    if (c > 0) {
#pragma unroll
        for (int dt = 0; dt < 4; dt++)
#pragma unroll
            for (int kk = 0; kk < 2; kk++) {
                const unsigned* sp = &Spk[(dt * 16 + lr) * 64 + kk * 32 + q * 8];
                uint4 pa = *(const uint4*)sp;
                uint4 pb = *(const uint4*)(sp + 4);
                unsigned pk[8] = { pa.x, pa.y, pa.z, pa.w, pb.x, pb.y, pb.z, pb.w };
                bf16x8 hi, lo;
#pragma unroll
                for (int u = 0; u < 8; u++) {
                    hi[u] = (short)(pk[u] & 0xffffu);
                    lo[u] = (short)(pk[u] >> 16);
                }
                accr[dt] = __builtin_amdgcn_mfma_f32_16x16x32_bf16(hi, bqf[kk], accr[dt], 0, 0, 0);
                accr[dt] = __builtin_amdgcn_mfma_f32_16x16x32_bf16(lo, bqf[kk], accr[dt], 0, 0, 0);
            }
    }
    {   // diag
        f32x4 accp[4] = {};
#pragma unroll
        for (int kk = 0; kk < 2; kk++)
#pragma unroll
            for (int jt = 0; jt < 4; jt++) {
                bf16x8 akf = *(const bf16x8*)&Ks[(jt * 16 + lr) * 72 + kk * 32 + q * 8];
                accp[jt] = __builtin_amdgcn_mfma_f32_16x16x32_bf16(akf, bqf[kk], accp[jt], 0, 0, 0);
            }
        const int ii = w * 16 + lr;
#pragma unroll
        for (int jt = 0; jt < 4; jt++) {
            const int jj = jt * 16 + q * 4;
            float v0 = (jj + 0 <= ii) ? accp[jt][0] : 0.0f;
            float v1 = (jj + 1 <= ii) ? accp[jt][1] : 0.0f;
            float v2 = (jj + 2 <= ii) ? accp[jt][2] : 0.0f;
            float v3 = (jj + 3 <= ii) ? accp[jt][3] : 0.0f;
            unsigned w0 = __builtin_amdgcn_perm(
                __float_as_uint(v1), __float_as_uint(v0), 0x07060302u);
            unsigned w1 = __builtin_amdgcn_perm(
                __float_as_uint(v3), __float_as_uint(v2), 0x07060302u);
            *(uint2*)&Ps[w][lr * 72 + jt * 16 + q * 4] = make_uint2(w0, w1);
        }
        asm volatile("s_waitcnt lgkmcnt(0)" ::: "memory");
#pragma unroll
        for (int kk = 0; kk < 2; kk++) {
            bf16x8 bpf = *(const bf16x8*)&Ps[w][lr * 72 + kk * 32 + q * 8];
#pragma unroll
            for (int dt = 0; dt < 4; dt++) {
                bf16x8 avf = *(const bf16x8*)&Vs[(dt * 16 + lr) * 72 + kk * 32 + q * 8];
                accr[dt] = __builtin_amdgcn_mfma_f32_16x16x32_bf16(avf, bpf, accr[dt], 0, 0, 0);
            }
        }
    }
    {   // per-head LN stats: unique (row, h) writer -> plain store
        float s1 = 0.f, s2 = 0.f;
#pragma unroll
        for (int dt = 0; dt < 4; dt++)
#pragma unroll
            for (int r = 0; r < 4; r++) {
                float v = accr[dt][r];
                s1 += v; s2 += v * v;
            }
        s1 += __shfl_down(s1, 32); s2 += __shfl_down(s2, 32);
        s1 += __shfl_down(s1, 16); s2 += __shfl_down(s2, 16);
        if (q == 0) {
            int row = b * 2048 + i0 + w * 16 + lr;
            *(float2*)&stats[((size_t)row * 16 + h) * 2] = make_float2(s1, s2);
        }
    }
    {   // write R bf16 in-place over K's staged region
        const int i = i0 + w * 16 + lr;
#pragma unroll
        for (int dt = 0; dt < 4; dt++) {
            f32x4 a = accr[dt];
            *(ushort4*)&R[(size_t)(b * 2048 + i) * 1024 + h * 64 + dt * 16 + q * 4] =
                make_ushort4(f2bf(a[0]), f2bf(a[1]), f2bf(a[2]), f2bf(a[3]));
        }
    }
}

// ---------------------------------------------------------------------------
// Output GEMM with fused LayerNorm+gate A-staging (separate kernel so the
// lean projection GEMM keeps its register budget). out fp32 = A' @ WoT + bo,
// A' = bf16(((R - mu) * inv * gamma + beta) * G).
// ---------------------------------------------------------------------------
struct GLArgs {
    const USHORT* A;          // R bf16
    const USHORT* G;
    const float*  gamma;
    const float*  beta;
    const float*  stats;      // [4096][16][2] per-head partials
    const USHORT* W;
    const float*  bias;
    float*        dst;
};

__global__ __launch_bounds__(256, 2) void k_gemm_ln(GLArgs ga) {
    const USHORT* __restrict__ BT = ga.W;
    __shared__ USHORT As[2][128 * 32];
    __shared__ USHORT Bs[2][128 * 32];
    const int tid = threadIdx.x;
    const int m0 = blockIdx.y * 128, n0 = blockIdx.x * 128;
    const int w = tid >> 6, l = tid & 63, lr = l & 15, q = l >> 4;
    const int wr = w >> 1, wc = w & 1;
    const int srow = tid >> 2, sco = (tid & 3) * 8;
    f32x4 acc[4][4] = {};
    float mu0, iv0, mu1, iv1;
    {
        float a1 = 0.f, a2 = 0.f, b1 = 0.f, b2 = 0.f;
        const float* p0 = &ga.stats[(size_t)(m0 + srow) * 32];
        const float* p1 = &ga.stats[(size_t)(m0 + srow + 64) * 32];
#pragma unroll
        for (int hh = 0; hh < 8; hh++) {
            float4 v0 = *(const float4*)(p0 + hh * 4);
            a1 += v0.x + v0.z; a2 += v0.y + v0.w;
            float4 v1 = *(const float4*)(p1 + hh * 4);
            b1 += v1.x + v1.z; b2 += v1.y + v1.w;
        }
        mu0 = a1 * (1.0f / 1024.0f);
        iv0 = rsqrtf(fmaxf(a2 * (1.0f / 1024.0f) - mu0 * mu0, 0.0f) + 1e-5f);
        mu1 = b1 * (1.0f / 1024.0f);
        iv1 = rsqrtf(fmaxf(b2 * (1.0f / 1024.0f) - mu1 * mu1, 0.0f) + 1e-5f);
    }
#define STAGE_LN(kt_, buf_)                                                      \
    do {                                                                         \
        const int kk0 = (kt_) * 32;                                              \
        float4 g0 = *(const float4*)&ga.gamma[kk0 + sco];                        \
        float4 g1 = *(const float4*)&ga.gamma[kk0 + sco + 4];                    \
        float4 b0 = *(const float4*)&ga.beta[kk0 + sco];                         \
        float4 b1 = *(const float4*)&ga.beta[kk0 + sco + 4];                     \
        float gmv[8] = {g0.x,g0.y,g0.z,g0.w,g1.x,g1.y,g1.z,g1.w};                \
        float btv[8] = {b0.x,b0.y,b0.z,b0.w,b1.x,b1.y,b1.z,b1.w};                \
        _Pragma("unroll")                                                        \
        for (int hrow = 0; hrow < 2; hrow++) {                                   \
            float mu = hrow ? mu1 : mu0, iv = hrow ? iv1 : iv0;                  \
            size_t off = (size_t)(m0 + srow + hrow * 64) * 1024 + kk0 + sco;     \
            USHORT r8[8], g8[8], a8[8];                                          \
            *(int4*)r8 = *(const int4*)&ga.A[off];                               \
            *(int4*)g8 = *(const int4*)&ga.G[off];                               \
            _Pragma("unroll")                                                    \
            for (int u = 0; u < 8; u++)                                          \
                a8[u] = f2bf(((bf2f(r8[u]) - mu) * iv * gmv[u] + btv[u])         \
                             * bf2f(g8[u]));                                     \
            *(int4*)&As[buf_][(srow + hrow * 64) * 32 + sco] = *(int4*)a8;       \
        }                                                                        \
        GLDS16(&BT[(size_t)(n0 + srow) * 1024 + kk0 + sco],                      \
               &Bs[buf_][srow * 32 + sco]);                                      \
        GLDS16(&BT[(size_t)(n0 + srow + 64) * 1024 + kk0 + sco],                 \
               &Bs[buf_][(srow + 64) * 32 + sco]);                               \
    } while (0)
    STAGE_LN(0, 0);
    for (int kt = 0; kt < 32; kt++) {
        const int cur = kt & 1;
        FULL_BARRIER();
        if (kt + 1 < 32) STAGE_LN(kt + 1, 1 - cur);
        bf16x8 af[4], bfr[4];
#pragma unroll
        for (int mi = 0; mi < 4; mi++)
            af[mi] = *(const bf16x8*)&As[cur][(wr * 64 + mi * 16 + lr) * 32 + q * 8];
#pragma unroll
        for (int ni = 0; ni < 4; ni++)
            bfr[ni] = *(const bf16x8*)&Bs[cur][(wc * 64 + ni * 16 + lr) * 32 + q * 8];
#pragma unroll
        for (int mi = 0; mi < 4; mi++)
#pragma unroll
            for (int ni = 0; ni < 4; ni++)
                acc[mi][ni] = __builtin_amdgcn_mfma_f32_16x16x32_bf16(
                    af[mi], bfr[ni], acc[mi][ni], 0, 0, 0);
    }
#undef STAGE_LN
#pragma unroll
    for (int ni = 0; ni < 4; ni++) {
        int col = n0 + wc * 64 + ni * 16 + lr;
        float bv = ga.bias[col];
#pragma unroll
        for (int mi = 0; mi < 4; mi++) {
            int r0 = m0 + wr * 64 + mi * 16 + q * 4;
#pragma unroll
            for (int r = 0; r < 4; r++)
                ga.dst[(size_t)(r0 + r) * 1024 + col] = acc[mi][ni][r] + bv;
        }
    }
}

// ---------------------------------------------------------------------------
extern "C" void kernel_launch(void* const* d_in, const int* in_sizes, int n_in,
                              void* d_out, int out_size, void* d_ws, size_t ws_size,
                              hipStream_t stream) {
    const float* x     = (const float*)d_in[0];
    const float* Wq    = (const float*)d_in[1];
    const float* bq    = (const float*)d_in[2];
    const float* Wk    = (const float*)d_in[3];
    const float* bk    = (const float*)d_in[4];
    const float* Wv    = (const float*)d_in[5];
    const float* bv    = (const float*)d_in[6];
    const float* Wg    = (const float*)d_in[7];
    const float* bg    = (const float*)d_in[8];
    const float* Wo    = (const float*)d_in[9];
    const float* bo    = (const float*)d_in[10];
    const float* gamma = (const float*)d_in[11];
    const float* beta  = (const float*)d_in[12];

    // ws (42.5 MB): WT x5 | Qb (Q'') | Kb -> R (in-place) | VTb | Gb | stats(512KB)
    char* ws = (char*)d_ws;
    const size_t MB = 1 << 20;
    USHORT* WqT = (USHORT*)(ws + 0 * MB);
    USHORT* WkT = (USHORT*)(ws + 2 * MB);
    USHORT* WvT = (USHORT*)(ws + 4 * MB);
    USHORT* WgT = (USHORT*)(ws + 6 * MB);
    USHORT* WoT = (USHORT*)(ws + 8 * MB);
    USHORT* Qb  = (USHORT*)(ws + 10 * MB);
    USHORT* Kb  = (USHORT*)(ws + 18 * MB);   // becomes R bf16 after k_apply
    USHORT* VTb = (USHORT*)(ws + 26 * MB);
    USHORT* Gb  = (USHORT*)(ws + 34 * MB);
    float*  Sts = (float*) (ws + 42 * MB);   // [4096][16][2] per-head partials
    USHORT* Xb  = (USHORT*)d_out;            // bf16 x; dead after proj
    float*  Ust = (float*)d_out;             // U slots (16 MB); dead after apply

    {   // 1. prep: transpose 5 weights + cast x
        PrepArgs pa;
        pa.src[0] = Wq; pa.src[1] = Wk; pa.src[2] = Wv; pa.src[3] = Wg; pa.src[4] = Wo;
        pa.dst[0] = WqT; pa.dst[1] = WkT; pa.dst[2] = WvT; pa.dst[3] = WgT; pa.dst[4] = WoT;
        pa.x = x; pa.xb = Xb;
        k_prep<<<dim3(16, 16, 6), 256, 0, stream>>>(pa);
    }
    {   // 2. fused projections: Q''(1/8 + row decay), K, VT(+col decay), G(sigmoid)
        GArgs ga;
        ga.A = Xb;
        ga.W[0] = WqT; ga.W[1] = WkT; ga.W[2] = WvT; ga.W[3] = WgT;
        ga.bias[0] = bq; ga.bias[1] = bk; ga.bias[2] = bv; ga.bias[3] = bg;
        ga.dst[0] = Qb; ga.dst[1] = Kb; ga.dst[2] = nullptr; ga.dst[3] = Gb;
        ga.dstv = VTb;
        ga.scale[0] = 0.125f; ga.scale[1] = 1.0f; ga.scale[2] = 1.0f; ga.scale[3] = 1.0f;
        ga.mode[0] = 4; ga.mode[1] = 0; ga.mode[2] = 2; ga.mode[3] = 1;
        k_gemm<<<dim3(8, 32, 4), 256, 0, stream>>>(ga);
    }
    // 3. chunk outer products U (into d_out; Xb dead)
    k_attn_u<<<dim3(32, 32), 256, 0, stream>>>(Kb, VTb, Ust);
    // 4. apply: scan + diag + cross + per-head LN stats; R bf16 in-place over Kb
    k_apply<<<dim3(32, 32), 256, 0, stream>>>(Qb, Kb, VTb, Ust, Kb, Sts);
    {   // 5. output projection with fused LN+gate staging -> d_out fp32
        GLArgs go;
        go.A = Kb; go.G = Gb; go.gamma = gamma; go.beta = beta; go.stats = Sts;
        go.W = WoT; go.bias = bo; go.dst = (float*)d_out;
        k_gemm_ln<<<dim3(8, 32, 1), 256, 0, stream>>>(go);
    }
}

// Round 13
// 217.377 us; speedup vs baseline: 1.1622x; 1.0718x over previous
//
#include <hip/hip_runtime.h>

typedef __attribute__((ext_vector_type(4))) float f32x4;
typedef __attribute__((ext_vector_type(8))) short bf16x8;
typedef unsigned short USHORT;

static __device__ __forceinline__ float bf2f(USHORT u) {
    return __uint_as_float(((unsigned)u) << 16);
}
static __device__ __forceinline__ USHORT f2bf(float f) {
    unsigned u = __float_as_uint(f);
    unsigned r = u + 0x7FFF + ((u >> 16) & 1);   // RTNE
    return (USHORT)(r >> 16);
}

#define GLDS16(gp, lp) __builtin_amdgcn_global_load_lds(                      \
    (const __attribute__((address_space(1))) unsigned int*)(gp),              \
    (__attribute__((address_space(3))) unsigned int*)(lp), 16, 0, 0)

#define FULL_BARRIER() asm volatile("s_waitcnt vmcnt(0) lgkmcnt(0)\ns_barrier" ::: "memory")

#define D64 0.52559648f              // 0.99^64
#define L2D (-0.014499569695115089f) // log2(0.99)

// ---------------------------------------------------------------------------
// Prep: z<5 -> transpose+cast weight z; z==5 -> cast x fp32->bf16.
// ---------------------------------------------------------------------------
struct PrepArgs { const float* src[5]; USHORT* dst[5]; const float* x; USHORT* xb; };

__global__ __launch_bounds__(256) void k_prep(PrepArgs pa) {
    const int z = blockIdx.z;
    const int tid = threadIdx.x;
    __shared__ USHORT t[64][65];
    if (z < 5) {
        const float* __restrict__ W  = pa.src[z];
        USHORT* __restrict__      WT = pa.dst[z];
        const int k0 = blockIdx.y * 64, n0 = blockIdx.x * 64;
#pragma unroll
        for (int s = 0; s < 4; s++) {
            int slot = tid + s * 256;
            int row = slot >> 4, c4 = (slot & 15) * 4;
            float4 vv = *(const float4*)&W[(size_t)(k0 + row) * 1024 + n0 + c4];
            t[row][c4 + 0] = f2bf(vv.x);
            t[row][c4 + 1] = f2bf(vv.y);
            t[row][c4 + 2] = f2bf(vv.z);
            t[row][c4 + 3] = f2bf(vv.w);
        }
        __syncthreads();
#pragma unroll
        for (int s = 0; s < 2; s++) {
            int slot = tid + s * 256;
            int n = slot >> 3, c8 = (slot & 7) * 8;
            USHORT tmp[8];
#pragma unroll
            for (int u = 0; u < 8; u++) tmp[u] = t[c8 + u][n];
            *(int4*)&WT[(size_t)(n0 + n) * 1024 + k0 + c8] = *(int4*)tmp;
        }
    } else {
        const int bi = blockIdx.y * 16 + blockIdx.x;
        const float* xs = pa.x + (size_t)bi * 16384;
        USHORT* xd = pa.xb + (size_t)bi * 16384;
#pragma unroll
        for (int u = 0; u < 16; u++) {
            int idx = u * 1024 + tid * 4;
            float4 v = *(const float4*)&xs[idx];
            *(ushort4*)&xd[idx] = make_ushort4(f2bf(v.x), f2bf(v.y), f2bf(v.z), f2bf(v.w));
        }
    }
}

// ---------------------------------------------------------------------------
// Lean GEMM (R9-proven): bf16 A via glds, dbuf pipeline.
// modes: 0 bf16*scale; 1 sigmoid bf16; 2 V->VT[b,h,d,s]*0.99^{-(s&63)}; 3 fp32.
// ---------------------------------------------------------------------------
struct GArgs {
    const USHORT* A;
    const USHORT* W[4];
    const float*  bias[4];
    void*         dst[4];
    USHORT*       dstv;
    float         scale[4];
    int           mode[4];
};

__global__ __launch_bounds__(256, 2) void k_gemm(GArgs ga) {
    const int z = blockIdx.z;
    const USHORT* __restrict__ A  = ga.A;
    const USHORT* __restrict__ BT = ga.W[z];
    __shared__ USHORT As[2][128 * 32];
    __shared__ USHORT Bs[2][128 * 32];
    const int tid = threadIdx.x;
    const int m0 = blockIdx.y * 128, n0 = blockIdx.x * 128;
    const int w = tid >> 6, l = tid & 63, lr = l & 15, q = l >> 4;
    const int wr = w >> 1, wc = w & 1;
    const int srow = tid >> 2, sco = (tid & 3) * 8;
    f32x4 acc[4][4] = {};
    GLDS16(&A [(size_t)(m0 + srow)      * 1024 + sco], &As[0][srow * 32 + sco]);
    GLDS16(&A [(size_t)(m0 + srow + 64) * 1024 + sco], &As[0][(srow + 64) * 32 + sco]);
    GLDS16(&BT[(size_t)(n0 + srow)      * 1024 + sco], &Bs[0][srow * 32 + sco]);
    GLDS16(&BT[(size_t)(n0 + srow + 64) * 1024 + sco], &Bs[0][(srow + 64) * 32 + sco]);
    for (int kt = 0; kt < 32; kt++) {
        const int cur = kt & 1;
        FULL_BARRIER();
        if (kt + 1 < 32) {
            const int k1 = (kt + 1) * 32;
            const int nxt = 1 - cur;
            GLDS16(&A [(size_t)(m0 + srow)      * 1024 + k1 + sco], &As[nxt][srow * 32 + sco]);
            GLDS16(&A [(size_t)(m0 + srow + 64) * 1024 + k1 + sco], &As[nxt][(srow + 64) * 32 + sco]);
            GLDS16(&BT[(size_t)(n0 + srow)      * 1024 + k1 + sco], &Bs[nxt][srow * 32 + sco]);
            GLDS16(&BT[(size_t)(n0 + srow + 64) * 1024 + k1 + sco], &Bs[nxt][(srow + 64) * 32 + sco]);
        }
        bf16x8 af[4], bfr[4];
#pragma unroll
        for (int mi = 0; mi < 4; mi++)
            af[mi] = *(const bf16x8*)&As[cur][(wr * 64 + mi * 16 + lr) * 32 + q * 8];
#pragma unroll
        for (int ni = 0; ni < 4; ni++)
            bfr[ni] = *(const bf16x8*)&Bs[cur][(wc * 64 + ni * 16 + lr) * 32 + q * 8];
#pragma unroll
        for (int mi = 0; mi < 4; mi++)
#pragma unroll
            for (int ni = 0; ni < 4; ni++)
                acc[mi][ni] = __builtin_amdgcn_mfma_f32_16x16x32_bf16(
                    af[mi], bfr[ni], acc[mi][ni], 0, 0, 0);
    }
    const float scale = ga.scale[z];
    const int mode = ga.mode[z];
    const float* __restrict__ bias = ga.bias[z];
#pragma unroll
    for (int ni = 0; ni < 4; ni++) {
        int col = n0 + wc * 64 + ni * 16 + lr;
        float bv = bias[col];
#pragma unroll
        for (int mi = 0; mi < 4; mi++) {
            int r0 = m0 + wr * 64 + mi * 16 + q * 4;
            float vr[4];
#pragma unroll
            for (int r = 0; r < 4; r++) {
                float v = acc[mi][ni][r] + bv;
                if (mode == 1) v = 1.0f / (1.0f + __expf(-v));
                vr[r] = v * scale;
            }
            if (mode == 3) {
                float* df = (float*)ga.dst[z];
#pragma unroll
                for (int r = 0; r < 4; r++)
                    df[(size_t)(r0 + r) * 1024 + col] = vr[r];
            } else if (mode == 2) {
                int b = r0 >> 11, s = r0 & 2047;
                int h = col >> 6, d = col & 63;
                const float NP1 = 1.0101010101010102f;
                float c0 = exp2f(-L2D * (float)(s & 63));
                float c1 = c0 * NP1, c2 = c1 * NP1, c3 = c2 * NP1;
                *(ushort4*)&ga.dstv[(size_t)(((b * 16 + h) * 64) + d) * 2048 + s] =
                    make_ushort4(f2bf(vr[0] * c0), f2bf(vr[1] * c1),
                                 f2bf(vr[2] * c2), f2bf(vr[3] * c3));
            } else {
                USHORT* db = (USHORT*)ga.dst[z];
#pragma unroll
                for (int r = 0; r < 4; r++)
                    db[(size_t)(r0 + r) * 1024 + col] = f2bf(vr[r]);
            }
        }
    }
}

// ---------------------------------------------------------------------------
// U_c = 0.99^64 * V'_c^T @ K_c  fp32 at slot (bh,c) in U (=d_out).
// ---------------------------------------------------------------------------
__global__ __launch_bounds__(256) void k_attn_u(const USHORT* __restrict__ K,
                                                const USHORT* __restrict__ VT,
                                                float* __restrict__ U) {
    const int bh = blockIdx.x, c = blockIdx.y;
    const int b = bh >> 4, h = bh & 15;
    const int tid = threadIdx.x, w = tid >> 6, l = tid & 63, lr = l & 15, q = l >> 4;
    __shared__ USHORT KT[64 * 72];
    __shared__ USHORT Vs[64 * 72];
#pragma unroll
    for (int s = 0; s < 2; s++) {
        int slot = tid + s * 256;
        int row = slot >> 3, co = (slot & 7) * 8;
        USHORT kv[8];
        *(int4*)kv = *(const int4*)&K[(size_t)(b * 2048 + c * 64 + row) * 1024 + h * 64 + co];
#pragma unroll
        for (int u = 0; u < 8; u++) KT[(co + u) * 72 + row] = kv[u];
        *(int4*)&Vs[row * 72 + co] =
            *(const int4*)&VT[(size_t)(bh * 64 + row) * 2048 + c * 64 + co];
    }
    __syncthreads();
    f32x4 acc[4] = {};
    bf16x8 av[2];
#pragma unroll
    for (int kk = 0; kk < 2; kk++)
        av[kk] = *(const bf16x8*)&Vs[(w * 16 + lr) * 72 + kk * 32 + q * 8];
#pragma unroll
    for (int dkt = 0; dkt < 4; dkt++)
#pragma unroll
        for (int kk = 0; kk < 2; kk++) {
            bf16x8 bk = *(const bf16x8*)&KT[(dkt * 16 + lr) * 72 + kk * 32 + q * 8];
            acc[dkt] = __builtin_amdgcn_mfma_f32_16x16x32_bf16(av[kk], bk, acc[dkt], 0, 0, 0);
        }
    float* slot = U + (size_t)(bh * 32 + c) * 4096;
#pragma unroll
    for (int dkt = 0; dkt < 4; dkt++)
#pragma unroll
        for (int r = 0; r < 4; r++)
            slot[(w * 16 + q * 4 + r) * 64 + dkt * 16 + lr] = acc[dkt][r] * D64;
}

// ---------------------------------------------------------------------------
// Apply: block (bh, c): scan U->S_{c-1}, diag masked tile, cross via S,
// per-head LN stats (unique writer), R bf16 in-place over K's staged region.
// Q row-decay (0.99^{local row}) folded into Qs staging here.
// ---------------------------------------------------------------------------
__global__ __launch_bounds__(256, 2) void k_apply(const USHORT* __restrict__ Q,
                                                  const USHORT* __restrict__ K,
                                                  const USHORT* __restrict__ VT,
                                                  const float* __restrict__ U,
                                                  USHORT* __restrict__ R,
                                                  float* __restrict__ stats) {
    const int bh = blockIdx.x, c = blockIdx.y;
    const int b = bh >> 4, h = bh & 15;
    const int i0 = c * 64;
    const int tid = threadIdx.x, w = tid >> 6, l = tid & 63, lr = l & 15, q = l >> 4;
    __shared__ USHORT Qs[64 * 72];
    __shared__ USHORT Ks[64 * 72];
    __shared__ USHORT Vs[64 * 72];
    __shared__ USHORT Ps[4][16 * 72];
    __shared__ unsigned Spk[4096];
#pragma unroll
    for (int s = 0; s < 2; s++) {
        int slot = tid + s * 256;
        int row = slot >> 3, c8 = (slot & 7) * 8;
        USHORT q8[8];
        *(int4*)q8 = *(const int4*)&Q[(size_t)(b * 2048 + i0 + row) * 1024 + h * 64 + c8];
        const float fr = exp2f(L2D * (float)row);   // Q'' = Q * 0.99^{local i}
#pragma unroll
        for (int u = 0; u < 8; u++) q8[u] = f2bf(bf2f(q8[u]) * fr);
        *(int4*)&Qs[row * 72 + c8] = *(int4*)q8;
        *(int4*)&Ks[row * 72 + c8] =
            *(const int4*)&K[(size_t)(b * 2048 + i0 + row) * 1024 + h * 64 + c8];
        *(int4*)&Vs[row * 72 + c8] =
            *(const int4*)&VT[(size_t)(bh * 64 + row) * 2048 + i0 + c8];
    }
    // scan: S_{c-1} = sum_{c'<c} D64^{c-1-c'} U_{c'}
    if (c > 0) {
        float sa[16] = {};
        const float* Ub = U + (size_t)bh * 32 * 4096 + tid * 16;
        for (int cp = 0; cp < c; cp++) {
            const float* p = Ub + (size_t)cp * 4096;
#pragma unroll
            for (int u4 = 0; u4 < 4; u4++) {
                float4 uv = *(const float4*)(p + u4 * 4);
                sa[u4 * 4 + 0] = sa[u4 * 4 + 0] * D64 + uv.x;
                sa[u4 * 4 + 1] = sa[u4 * 4 + 1] * D64 + uv.y;
                sa[u4 * 4 + 2] = sa[u4 * 4 + 2] * D64 + uv.z;
                sa[u4 * 4 + 3] = sa[u4 * 4 + 3] * D64 + uv.w;
            }
        }
#pragma unroll
        for (int u = 0; u < 16; u++) {
            USHORT hi = f2bf(sa[u]);
            float  lo = sa[u] - bf2f(hi);
            Spk[tid * 16 + u] = (unsigned)hi | ((unsigned)f2bf(lo) << 16);
        }
    }
    __syncthreads();
    bf16x8 bqf[2];
#pragma unroll
    for (int kk = 0; kk < 2; kk++)
        bqf[kk] = *(const bf16x8*)&Qs[(w * 16 + lr) * 72 + kk * 32 + q * 8];
    f32x4 accr[4] = {};
    if (c > 0) {
#pragma unroll
        for (int dt = 0; dt < 4; dt++)
#pragma unroll
            for (int kk = 0; kk < 2; kk++) {
                const unsigned* sp = &Spk[(dt * 16 + lr) * 64 + kk * 32 + q * 8];
                uint4 pa = *(const uint4*)sp;
                uint4 pb = *(const uint4*)(sp + 4);
                unsigned pk[8] = { pa.x, pa.y, pa.z, pa.w, pb.x, pb.y, pb.z, pb.w };
                bf16x8 hi, lo;
#pragma unroll
                for (int u = 0; u < 8; u++) {
                    hi[u] = (short)(pk[u] & 0xffffu);
                    lo[u] = (short)(pk[u] >> 16);
                }
                accr[dt] = __builtin_amdgcn_mfma_f32_16x16x32_bf16(hi, bqf[kk], accr[dt], 0, 0, 0);
                accr[dt] = __builtin_amdgcn_mfma_f32_16x16x32_bf16(lo, bqf[kk], accr[dt], 0, 0, 0);
            }
    }
    {   // diag
        f32x4 accp[4] = {};
#pragma unroll
        for (int kk = 0; kk < 2; kk++)
#pragma unroll
            for (int jt = 0; jt < 4; jt++) {
                bf16x8 akf = *(const bf16x8*)&Ks[(jt * 16 + lr) * 72 + kk * 32 + q * 8];
                accp[jt] = __builtin_amdgcn_mfma_f32_16x16x32_bf16(akf, bqf[kk], accp[jt], 0, 0, 0);
            }
        const int ii = w * 16 + lr;
#pragma unroll
        for (int jt = 0; jt < 4; jt++) {
            const int jj = jt * 16 + q * 4;
            float v0 = (jj + 0 <= ii) ? accp[jt][0] : 0.0f;
            float v1 = (jj + 1 <= ii) ? accp[jt][1] : 0.0f;
            float v2 = (jj + 2 <= ii) ? accp[jt][2] : 0.0f;
            float v3 = (jj + 3 <= ii) ? accp[jt][3] : 0.0f;
            unsigned w0 = __builtin_amdgcn_perm(
                __float_as_uint(v1), __float_as_uint(v0), 0x07060302u);
            unsigned w1 = __builtin_amdgcn_perm(
                __float_as_uint(v3), __float_as_uint(v2), 0x07060302u);
            *(uint2*)&Ps[w][lr * 72 + jt * 16 + q * 4] = make_uint2(w0, w1);
        }
        asm volatile("s_waitcnt lgkmcnt(0)" ::: "memory");
#pragma unroll
        for (int kk = 0; kk < 2; kk++) {
            bf16x8 bpf = *(const bf16x8*)&Ps[w][lr * 72 + kk * 32 + q * 8];
#pragma unroll
            for (int dt = 0; dt < 4; dt++) {
                bf16x8 avf = *(const bf16x8*)&Vs[(dt * 16 + lr) * 72 + kk * 32 + q * 8];
                accr[dt] = __builtin_amdgcn_mfma_f32_16x16x32_bf16(avf, bpf, accr[dt], 0, 0, 0);
            }
        }
    }
    {   // per-head LN stats: unique (row, h) writer
        float s1 = 0.f, s2 = 0.f;
#pragma unroll
        for (int dt = 0; dt < 4; dt++)
#pragma unroll
            for (int r = 0; r < 4; r++) {
                float v = accr[dt][r];
                s1 += v; s2 += v * v;
            }
        s1 += __shfl_down(s1, 32); s2 += __shfl_down(s2, 32);
        s1 += __shfl_down(s1, 16); s2 += __shfl_down(s2, 16);
        if (q == 0) {
            int row = b * 2048 + i0 + w * 16 + lr;
            *(float2*)&stats[((size_t)row * 16 + h) * 2] = make_float2(s1, s2);
        }
    }
    {   // write R bf16 in-place over K's staged region
        const int i = i0 + w * 16 + lr;
#pragma unroll
        for (int dt = 0; dt < 4; dt++) {
            f32x4 a = accr[dt];
            *(ushort4*)&R[(size_t)(b * 2048 + i) * 1024 + h * 64 + dt * 16 + q * 4] =
                make_ushort4(f2bf(a[0]), f2bf(a[1]), f2bf(a[2]), f2bf(a[3]));
        }
    }
}

// ---------------------------------------------------------------------------
// LayerNorm + gate (standalone, R9-proven shape). Sums 16 per-head stat
// partials per row, normalizes R bf16, multiplies gate, writes NG bf16.
// ---------------------------------------------------------------------------
__global__ __launch_bounds__(256) void k_ln_gate(const USHORT* __restrict__ R,
                                                 const USHORT* __restrict__ G,
                                                 const float* __restrict__ stats,
                                                 const float* __restrict__ gamma,
                                                 const float* __restrict__ beta,
                                                 USHORT* __restrict__ NG) {
    const int row = blockIdx.x, tid = threadIdx.x;
    float s1 = 0.f, s2 = 0.f;
    const float* sp = &stats[(size_t)row * 32];
#pragma unroll
    for (int hh = 0; hh < 8; hh++) {
        float4 v = *(const float4*)(sp + hh * 4);
        s1 += v.x + v.z; s2 += v.y + v.w;
    }
    const float mu  = s1 * (1.0f / 1024.0f);
    const float var = s2 * (1.0f / 1024.0f) - mu * mu;
    const float inv = rsqrtf(fmaxf(var, 0.0f) + 1e-5f);
    ushort4 rv = *(const ushort4*)&R[(size_t)row * 1024 + tid * 4];
    ushort4 g4 = *(const ushort4*)&G[(size_t)row * 1024 + tid * 4];
    float4 gm = *(const float4*)&gamma[tid * 4];
    float4 bt = *(const float4*)&beta[tid * 4];
    float  vv[4]  = { bf2f(rv.x), bf2f(rv.y), bf2f(rv.z), bf2f(rv.w) };
    USHORT gg[4]  = { g4.x, g4.y, g4.z, g4.w };
    float  gmm[4] = { gm.x, gm.y, gm.z, gm.w };
    float  btt[4] = { bt.x, bt.y, bt.z, bt.w };
    USHORT o4[4];
#pragma unroll
    for (int u = 0; u < 4; u++) {
        float nv = (vv[u] - mu) * inv * gmm[u] + btt[u];
        o4[u] = f2bf(nv * bf2f(gg[u]));
    }
    *(ushort4*)&NG[(size_t)row * 1024 + tid * 4] = make_ushort4(o4[0], o4[1], o4[2], o4[3]);
}

// ---------------------------------------------------------------------------
extern "C" void kernel_launch(void* const* d_in, const int* in_sizes, int n_in,
                              void* d_out, int out_size, void* d_ws, size_t ws_size,
                              hipStream_t stream) {
    const float* x     = (const float*)d_in[0];
    const float* Wq    = (const float*)d_in[1];
    const float* bq    = (const float*)d_in[2];
    const float* Wk    = (const float*)d_in[3];
    const float* bk    = (const float*)d_in[4];
    const float* Wv    = (const float*)d_in[5];
    const float* bv    = (const float*)d_in[6];
    const float* Wg    = (const float*)d_in[7];
    const float* bg    = (const float*)d_in[8];
    const float* Wo    = (const float*)d_in[9];
    const float* bo    = (const float*)d_in[10];
    const float* gamma = (const float*)d_in[11];
    const float* beta  = (const float*)d_in[12];

    // ws (42.5 MB): WT x5 | Qb -> NGb | Kb -> R (in-place) | VTb | Gb | stats
    char* ws = (char*)d_ws;
    const size_t MB = 1 << 20;
    USHORT* WqT = (USHORT*)(ws + 0 * MB);
    USHORT* WkT = (USHORT*)(ws + 2 * MB);
    USHORT* WvT = (USHORT*)(ws + 4 * MB);
    USHORT* WgT = (USHORT*)(ws + 6 * MB);
    USHORT* WoT = (USHORT*)(ws + 8 * MB);
    USHORT* Qb  = (USHORT*)(ws + 10 * MB);
    USHORT* Kb  = (USHORT*)(ws + 18 * MB);   // becomes R bf16 after k_apply
    USHORT* VTb = (USHORT*)(ws + 26 * MB);
    USHORT* Gb  = (USHORT*)(ws + 34 * MB);
    float*  Sts = (float*) (ws + 42 * MB);   // [4096][16][2] per-head partials
    USHORT* NGb = Qb;                        // Qb dead after apply
    USHORT* Xb  = (USHORT*)d_out;            // bf16 x; dead after proj
    float*  Ust = (float*)d_out;             // U slots; dead after apply

    {   // 1. prep: transpose 5 weights + cast x
        PrepArgs pa;
        pa.src[0] = Wq; pa.src[1] = Wk; pa.src[2] = Wv; pa.src[3] = Wg; pa.src[4] = Wo;
        pa.dst[0] = WqT; pa.dst[1] = WkT; pa.dst[2] = WvT; pa.dst[3] = WgT; pa.dst[4] = WoT;
        pa.x = x; pa.xb = Xb;
        k_prep<<<dim3(16, 16, 6), 256, 0, stream>>>(pa);
    }
    {   // 2. fused projections (R9 mode set): Q (0.125), K, VT(+col decay), G (sigmoid)
        GArgs ga;
        ga.A = Xb;
        ga.W[0] = WqT; ga.W[1] = WkT; ga.W[2] = WvT; ga.W[3] = WgT;
        ga.bias[0] = bq; ga.bias[1] = bk; ga.bias[2] = bv; ga.bias[3] = bg;
        ga.dst[0] = Qb; ga.dst[1] = Kb; ga.dst[2] = nullptr; ga.dst[3] = Gb;
        ga.dstv = VTb;
        ga.scale[0] = 0.125f; ga.scale[1] = 1.0f; ga.scale[2] = 1.0f; ga.scale[3] = 1.0f;
        ga.mode[0] = 0; ga.mode[1] = 0; ga.mode[2] = 2; ga.mode[3] = 1;
        k_gemm<<<dim3(8, 32, 4), 256, 0, stream>>>(ga);
    }
    // 3. chunk outer products U (into d_out; Xb dead)
    k_attn_u<<<dim3(32, 32), 256, 0, stream>>>(Kb, VTb, Ust);
    // 4. apply: scan + diag + cross + per-head LN stats; R bf16 in-place over Kb
    k_apply<<<dim3(32, 32), 256, 0, stream>>>(Qb, Kb, VTb, Ust, Kb, Sts);
    // 5. LayerNorm + gate -> NGb (= dead Qb)
    k_ln_gate<<<4096, 256, 0, stream>>>(Kb, Gb, Sts, gamma, beta, NGb);
    {   // 6. lean output projection (mode 3) -> d_out fp32
        GArgs go;
        go.A = NGb;
        for (int i = 0; i < 4; i++) {
            go.W[i] = WoT; go.bias[i] = bo; go.dst[i] = d_out;
            go.scale[i] = 1.0f; go.mode[i] = 3;
        }
        go.dstv = nullptr;
        k_gemm<<<dim3(8, 32, 1), 256, 0, stream>>>(go);
    }
}